// Round 1
// baseline (196.968 us; speedup 1.0000x reference)
//
#include <hip/hip_runtime.h>
#include <stdint.h>

#define S_LEN 2048
#define BATCH 2
#define DMODEL 1024
#define NHEAD 16
#define DHEAD 64
#define SCALE 0.125f

typedef float f32x4 __attribute__((ext_vector_type(4)));
typedef __bf16 bf16x8 __attribute__((ext_vector_type(8)));

__device__ __forceinline__ unsigned short f2bf(float f) {
  union { float f; unsigned int u; } v;
  v.f = f;
  unsigned int u = v.u;
  return (unsigned short)((u + 0x7fffu + ((u >> 16) & 1u)) >> 16);
}

__device__ __forceinline__ void gld16(const void* g, void* l) {
  __builtin_amdgcn_global_load_lds((__attribute__((address_space(1))) void*)(g),
                                   (__attribute__((address_space(3))) void*)(l),
                                   16, 0, 0);
}

// ---------------- fp32 -> bf16 pack ----------------
__global__ void cvt_kernel(const float* __restrict__ src, unsigned short* __restrict__ dst) {
  const int i = (blockIdx.x * 256 + threadIdx.x) * 4;
  const float4 v = *(const float4*)(src + i);
  ushort4 o;
  o.x = f2bf(v.x); o.y = f2bf(v.y); o.z = f2bf(v.z); o.w = f2bf(v.w);
  *(ushort4*)(dst + i) = o;
}

// ---------------- GEMM: C[m,n] = sum_k A[m,k]*W[n,k] (+bias) ----------------
// MODE 0: z=blockIdx.z in {0,1,2} selects Q/K/V; epilogue scatters bf16 to
//         qw/kw ([bh][s][dk]) and vtw ([bh][dk][s]).
// MODE 1: epilogue writes fp32 to outp[m*N+n] + bias.
template <int MODE>
__global__ __launch_bounds__(256, 2) void gemm_bt(
    const unsigned short* __restrict__ Abase,
    const unsigned short* __restrict__ Wbase,
    const float* __restrict__ bias0, const float* __restrict__ bias1,
    const float* __restrict__ bias2,
    unsigned short* __restrict__ qw, unsigned short* __restrict__ kw,
    unsigned short* __restrict__ vtw, float* __restrict__ outp) {
  constexpr int M = S_LEN * BATCH;  // 4096
  constexpr int N = DMODEL;         // 1024
  constexpr int K = DMODEL;         // 1024
  __shared__ unsigned short At[128 * 32];
  __shared__ unsigned short Bt[128 * 32];

  const int m0 = blockIdx.x * 128;
  const int n0 = blockIdx.y * 128;
  const int z = (MODE == 0) ? blockIdx.z : 0;
  const unsigned short* A = Abase + (size_t)z * M * K;
  const unsigned short* W = Wbase + (size_t)z * N * K;
  const float* bias = (z == 0 ? bias0 : (z == 1 ? bias1 : bias2));

  const int tid = threadIdx.x;
  const int w = tid >> 6, l = tid & 63;
  const int wr = w >> 1, wc = w & 1;
  const int lr = l & 15, lg = l >> 4;

  const int srow = tid >> 2;       // 0..63
  const int scol = (tid & 3) * 8;  // element col within 32-wide k tile

  f32x4 acc[4][4] = {};

  for (int k0 = 0; k0 < K; k0 += 32) {
    {
      const unsigned short* ga0 = A + (size_t)(m0 + srow) * K + k0 + scol;
      const unsigned short* ga1 = A + (size_t)(m0 + 64 + srow) * K + k0 + scol;
      const unsigned short* gb0 = W + (size_t)(n0 + srow) * K + k0 + scol;
      const unsigned short* gb1 = W + (size_t)(n0 + 64 + srow) * K + k0 + scol;
      char* la = (char*)At + w * 1024;
      char* lb = (char*)Bt + w * 1024;
      gld16(ga0, la);
      gld16(ga1, la + 4096);
      gld16(gb0, lb);
      gld16(gb1, lb + 4096);
    }
    __syncthreads();
    bf16x8 af[4], bfr[4];
#pragma unroll
    for (int mt = 0; mt < 4; ++mt)
      af[mt] = *(const bf16x8*)&At[(wr * 64 + mt * 16 + lr) * 32 + lg * 8];
#pragma unroll
    for (int nt = 0; nt < 4; ++nt)
      bfr[nt] = *(const bf16x8*)&Bt[(wc * 64 + nt * 16 + lr) * 32 + lg * 8];
#pragma unroll
    for (int mt = 0; mt < 4; ++mt)
#pragma unroll
      for (int nt = 0; nt < 4; ++nt)
        acc[mt][nt] = __builtin_amdgcn_mfma_f32_16x16x32_bf16(af[mt], bfr[nt], acc[mt][nt], 0, 0, 0);
    __syncthreads();
  }

#pragma unroll
  for (int mt = 0; mt < 4; ++mt) {
#pragma unroll
    for (int nt = 0; nt < 4; ++nt) {
#pragma unroll
      for (int r = 0; r < 4; ++r) {
        const int gm = m0 + wr * 64 + mt * 16 + lg * 4 + r;
        const int gn = n0 + wc * 64 + nt * 16 + lr;
        const float v = acc[mt][nt][r] + bias[gn];
        if (MODE == 1) {
          outp[(size_t)gm * N + gn] = v;
        } else {
          const int s = gm >> 1, bb = gm & 1;
          const int h = gn >> 6, dk = gn & 63;
          const int bh = bb * NHEAD + h;
          const unsigned short bv_ = f2bf(v);
          if (z == 0)
            qw[((size_t)bh * S_LEN + s) * DHEAD + dk] = bv_;
          else if (z == 1)
            kw[((size_t)bh * S_LEN + s) * DHEAD + dk] = bv_;
          else
            vtw[((size_t)bh * DHEAD + dk) * S_LEN + s] = bv_;
        }
      }
    }
  }
}

// ---------------- causal flash attention ----------------
// grid: (qtile 0..31, bh 0..31), 256 threads = 4 waves, wave w owns 16 q-rows.
__global__ __launch_bounds__(256, 2) void attn_kernel(
    const unsigned short* __restrict__ qw, const unsigned short* __restrict__ kw,
    const unsigned short* __restrict__ vtw, unsigned short* __restrict__ x2) {
  __shared__ unsigned short klds[64 * 64];        // [kv][d], XOR-swizzled 16B chunks
  __shared__ unsigned short vlds[64 * 64];        // [dk][kv], XOR-swizzled
  __shared__ unsigned short plds[4][16 * 72];     // per-wave P strip, padded

  const int qt = blockIdx.x;
  const int bh = blockIdx.y;
  const int bb = bh >> 4, h = bh & 15;
  const int tid = threadIdx.x;
  const int w = tid >> 6, l = tid & 63;
  const int lr = l & 15, lg = l >> 4;

  const size_t qkbase = (size_t)bh * S_LEN * DHEAD;
  const int qrow = qt * 64 + w * 16 + lr;
  bf16x8 qa[2];
  qa[0] = *(const bf16x8*)&qw[qkbase + (size_t)qrow * DHEAD + lg * 8];
  qa[1] = *(const bf16x8*)&qw[qkbase + (size_t)qrow * DHEAD + 32 + lg * 8];

  f32x4 oacc[4] = {};
  float Mr[4], Lr[4];
#pragma unroll
  for (int r = 0; r < 4; ++r) { Mr[r] = -3e38f; Lr[r] = 0.f; }

  const int srow = tid >> 3;     // 0..31
  const int schunk = tid & 7;

  for (int kt = 0; kt <= qt; ++kt) {
#pragma unroll
    for (int c = 0; c < 2; ++c) {
      const int row = c * 32 + srow;
      const int ch = schunk ^ (row & 7);  // pre-swizzled global source (rule #21)
      const unsigned short* gk = kw + qkbase + (size_t)(kt * 64 + row) * DHEAD + ch * 8;
      const unsigned short* gv = vtw + ((size_t)bh * DHEAD + row) * S_LEN + kt * 64 + ch * 8;
      gld16(gk, (char*)klds + c * 4096 + w * 1024);
      gld16(gv, (char*)vlds + c * 4096 + w * 1024);
    }
    __syncthreads();

    // QK^T: D[i][j], i = q-row (lg*4+r), j = k-col (lr)
    float sc[4][4];
#pragma unroll
    for (int ct = 0; ct < 4; ++ct) {
      const int row = ct * 16 + lr;
      const int sw = row & 7;
      const bf16x8 kb0 = *(const bf16x8*)((const char*)klds + row * 128 + ((0 + lg) ^ sw) * 16);
      const bf16x8 kb1 = *(const bf16x8*)((const char*)klds + row * 128 + ((4 + lg) ^ sw) * 16);
      f32x4 s = {};
      s = __builtin_amdgcn_mfma_f32_16x16x32_bf16(qa[0], kb0, s, 0, 0, 0);
      s = __builtin_amdgcn_mfma_f32_16x16x32_bf16(qa[1], kb1, s, 0, 0, 0);
#pragma unroll
      for (int r = 0; r < 4; ++r) sc[ct][r] = s[r] * SCALE;
    }
    if (kt == qt) {  // causal mask on the diagonal tile
#pragma unroll
      for (int ct = 0; ct < 4; ++ct) {
        const int kj = ct * 16 + lr;
#pragma unroll
        for (int r = 0; r < 4; ++r) {
          const int qi = w * 16 + lg * 4 + r;
          if (kj > qi) sc[ct][r] = -3e38f;
        }
      }
    }
    // online softmax (rows live on 16-lane groups)
    float tmax[4];
#pragma unroll
    for (int r = 0; r < 4; ++r) {
      float t = fmaxf(fmaxf(sc[0][r], sc[1][r]), fmaxf(sc[2][r], sc[3][r]));
#pragma unroll
      for (int msk = 1; msk <= 8; msk <<= 1) t = fmaxf(t, __shfl_xor(t, msk, 64));
      tmax[r] = t;
    }
    float resc[4];
#pragma unroll
    for (int r = 0; r < 4; ++r) {
      const float nm = fmaxf(Mr[r], tmax[r]);
      resc[r] = __expf(Mr[r] - nm);
      Mr[r] = nm;
      float su = 0.f;
#pragma unroll
      for (int ct = 0; ct < 4; ++ct) {
        const float p = __expf(sc[ct][r] - nm);
        sc[ct][r] = p;
        su += p;
      }
#pragma unroll
      for (int msk = 1; msk <= 8; msk <<= 1) su += __shfl_xor(su, msk, 64);
      Lr[r] = Lr[r] * resc[r] + su;
    }
#pragma unroll
    for (int nt = 0; nt < 4; ++nt)
#pragma unroll
      for (int r = 0; r < 4; ++r) oacc[nt][r] *= resc[r];

    // P: C-layout -> LDS -> A-layout
    unsigned short* pw = &plds[w][0];
#pragma unroll
    for (int ct = 0; ct < 4; ++ct)
#pragma unroll
      for (int r = 0; r < 4; ++r)
        pw[(lg * 4 + r) * 72 + ct * 16 + lr] = f2bf(sc[ct][r]);
    const bf16x8 pa0 = *(const bf16x8*)&pw[lr * 72 + lg * 8];
    const bf16x8 pa1 = *(const bf16x8*)&pw[lr * 72 + 32 + lg * 8];

    // PV: O[i][dk] += P[i][kv] * V[kv][dk]  (B-frag from vlds[dk][kv])
#pragma unroll
    for (int nt = 0; nt < 4; ++nt) {
      const int row = nt * 16 + lr;
      const int sw = row & 7;
      const bf16x8 vb0 = *(const bf16x8*)((const char*)vlds + row * 128 + ((0 + lg) ^ sw) * 16);
      const bf16x8 vb1 = *(const bf16x8*)((const char*)vlds + row * 128 + ((4 + lg) ^ sw) * 16);
      oacc[nt] = __builtin_amdgcn_mfma_f32_16x16x32_bf16(pa0, vb0, oacc[nt], 0, 0, 0);
      oacc[nt] = __builtin_amdgcn_mfma_f32_16x16x32_bf16(pa1, vb1, oacc[nt], 0, 0, 0);
    }
    __syncthreads();
  }

#pragma unroll
  for (int r = 0; r < 4; ++r) {
    const float inv = 1.0f / Lr[r];
    const int qi = qt * 64 + w * 16 + lg * 4 + r;
    const size_t mrow = (size_t)qi * BATCH + bb;
#pragma unroll
    for (int nt = 0; nt < 4; ++nt)
      x2[mrow * DMODEL + h * DHEAD + nt * 16 + lr] = f2bf(oacc[nt][r] * inv);
  }
}

extern "C" void kernel_launch(void* const* d_in, const int* in_sizes, int n_in,
                              void* d_out, int out_size, void* d_ws, size_t ws_size,
                              hipStream_t stream) {
  (void)in_sizes; (void)n_in; (void)out_size;
  if (ws_size < (size_t)67108864) return;  // need 64 MB scratch

  const float* query = (const float*)d_in[0];
  const float* key_  = (const float*)d_in[1];
  const float* value = (const float*)d_in[2];
  // d_in[3] = mask (tril) — causality is hardcoded
  const float* Wq = (const float*)d_in[4];
  const float* bq = (const float*)d_in[5];
  const float* Wk = (const float*)d_in[6];
  const float* bk = (const float*)d_in[7];
  const float* Wv = (const float*)d_in[8];
  const float* bv = (const float*)d_in[9];
  const float* Wo = (const float*)d_in[10];
  const float* bo = (const float*)d_in[11];

  char* ws = (char*)d_ws;
  unsigned short* xp = (unsigned short*)(ws);              // [3][4096][1024] bf16
  unsigned short* wp = (unsigned short*)(ws + 25165824);   // [3][1024][1024] bf16
  unsigned short* wo = (unsigned short*)(ws + 31457280);   // [1024][1024] bf16
  unsigned short* qws = (unsigned short*)(ws + 33554432);  // [32][2048][64] bf16
  unsigned short* kws = (unsigned short*)(ws + 41943040);  // [32][2048][64] bf16
  unsigned short* vtw = (unsigned short*)(ws + 50331648);  // [32][64][2048] bf16
  unsigned short* x2 = (unsigned short*)(ws + 58720256);   // [4096][1024] bf16

  const int NX = S_LEN * BATCH * DMODEL;  // 4194304
  const int NW = DMODEL * DMODEL;         // 1048576
  cvt_kernel<<<NX / 1024, 256, 0, stream>>>(query, xp);
  cvt_kernel<<<NX / 1024, 256, 0, stream>>>(key_, xp + (size_t)NX);
  cvt_kernel<<<NX / 1024, 256, 0, stream>>>(value, xp + 2 * (size_t)NX);
  cvt_kernel<<<NW / 1024, 256, 0, stream>>>(Wq, wp);
  cvt_kernel<<<NW / 1024, 256, 0, stream>>>(Wk, wp + (size_t)NW);
  cvt_kernel<<<NW / 1024, 256, 0, stream>>>(Wv, wp + 2 * (size_t)NW);
  cvt_kernel<<<NW / 1024, 256, 0, stream>>>(Wo, wo);

  gemm_bt<0><<<dim3(32, 8, 3), 256, 0, stream>>>(xp, wp, bq, bk, bv, qws, kws, vtw, nullptr);
  attn_kernel<<<dim3(32, 32), 256, 0, stream>>>(qws, kws, vtw, x2);
  gemm_bt<1><<<dim3(32, 8, 1), 256, 0, stream>>>(x2, wo, bo, bo, bo, nullptr, nullptr, nullptr,
                                                 (float*)d_out);
}